// Round 8
// baseline (2875.405 us; speedup 1.0000x reference)
//
#include <hip/hip_runtime.h>
#include <stdint.h>

#define NN 2048
#define TT 365
#define DD 16
#define HH 64
#define NBLK 128      // 16 rows per block, 1 block/CU (LDS-bound)
#define NTHR 1024     // 16 waves
#define SMEM_BYTES 152192
#define QSLOT_U32 65536          // 256 KB per ring slot: [128 blocks][2KB chunk]
#define SENT32 0xFFFFFFFFu       // bf16 NaN pair: unreachable for tanh output

typedef __attribute__((ext_vector_type(8))) short bf16x8;
typedef __attribute__((ext_vector_type(4))) float f32x4;
typedef __attribute__((ext_vector_type(4))) unsigned int u32x4;

__device__ __forceinline__ unsigned short f2bf(float f) {
  union { float f; uint32_t u; } z; z.f = f;
  uint32_t r = z.u + 0x7fffu + ((z.u >> 16) & 1u);
  return (unsigned short)(r >> 16);
}
__device__ __forceinline__ float sigmoid_(float x) { return 1.f / (1.f + __expf(-x)); }
__device__ __forceinline__ float tanh_(float x) {
  float ax = fabsf(x);
  float e = __expf(-2.f * ax);
  float r = (1.f - e) / (1.f + e);
  return x < 0.f ? -r : r;
}
__device__ __forceinline__ bf16x8 asbf(u32x4 v) { return __builtin_bit_cast(bf16x8, v); }

// R21 = R20 (block-major ring, reg-staged Out, X pair-read; 2185us) + two
// serial-chain cuts:
//  (1) gate-interleaved weights (R18/R19's verified indices): all 4 gates of
//      a logical col in 4 adjacent lanes -> epilogue is intra-wave shfl;
//      B1/B2 barriers + sh_g LDS round trip DELETED (2 barriers/step left).
//      q-issue stays AT acquire (R18's regression was early-issue, not this).
//  (2) in-order per-chunk validate+retry+MFMA: one initial 16-chunk load,
//      then consume in fixed order; only actual straggler chunks re-loaded
//      (not all pending), MFMAs of ready chunks overlap straggler RT.
//      Deterministic accumulation order (absmax must stay 0.00390625).
// Protocol: R17 flag-free sentinel ring (write-once, 366 slots).
__global__ __launch_bounds__(NTHR) __attribute__((amdgpu_waves_per_eu(4, 4)))
void rgcn_persist(
    const float* __restrict__ X, const float* __restrict__ Af,
    const float* __restrict__ Wih, const float* __restrict__ Whh,
    const float* __restrict__ Bias, const float* __restrict__ Wq,
    const float* __restrict__ Bq, const float* __restrict__ Wd,
    const float* __restrict__ Bd, float* __restrict__ Out,
    uint32_t* qRing, uint32_t* flags, int rdepth, int ringfull)
{
  extern __shared__ __align__(16) char smem[];
  unsigned short* afrag = (unsigned short*)smem;                 // [64kc][64ln][8] 65536
  unsigned short* whxT  = (unsigned short*)(smem + 65536);       // [256n][104k]    53248
  unsigned short* wqT   = (unsigned short*)(smem + 118784);      // [64n][72k]       9216
  f32x4*          sh_part = (f32x4*)(smem + 128000);             // [16][65] f32x4  16640
  float*          shf32 = (float*)(smem + 144640);               // [16][65] f32 h   4160
  unsigned short* sh_hx = (unsigned short*)(smem + 148800);      // [16][104] bf16   3328
  unsigned int*   cnt   = (unsigned int*)(smem + 152128);        // fallback arrival ctr

  const int tid = threadIdx.x;
  const int w = tid >> 6;        // wave 0..15
  const int c = tid & 63;        // lane
  const int base = blockIdx.x * 16;
  const int m = c & 15, quad = c >> 4;
  const int nt = w & 3, kh = w >> 2;                       // phase B tile coords

  // ---- one-time staging ----
  for (int i = tid; i < 256 * 104; i += NTHR) {            // [WhhT|WihT|0], gate-interleaved
    int n = i / 104, k = i - n * 104;                      // n = PHYSICAL col
    int src = (n & 3) * 64 + (n >> 2);                     // logical source col
    float v = (k < 64) ? Whh[k * 256 + src] : (k < 80) ? Wih[(k - 64) * 256 + src] : 0.f;
    whxT[i] = f2bf(v);
  }
  for (int i = tid; i < 64 * 72; i += NTHR) {              // WqT (pad k 64..71 = 0)
    int n = i / 72, k = i - n * 72;
    wqT[i] = (k < 64) ? f2bf(Wq[k * 64 + n]) : (unsigned short)0;
  }
  for (int i = tid; i < 16 * NN; i += NTHR) {              // A -> MFMA A-frag layout
    int r = i >> 11, k = i & (NN - 1);
    afrag[(k >> 5) * 512 + (((k >> 3) & 3) * 16 + r) * 8 + (k & 7)] =
        f2bf(Af[(size_t)(base + r) * NN + k]);
  }
  for (int i = tid; i < 16 * 104; i += NTHR) sh_hx[i] = 0; // h=0, x below, pad=0
  __syncthreads();
  if (c < 16) sh_hx[w * 104 + 64 + c] = f2bf(X[(size_t)(base + w) * (TT * DD) + c]);
  if (tid == 0) *cnt = 0u;
  __syncthreads();

  // per-lane gate constants (interleaved layout): phys col p = 16w+m
  const float bgate = Bias[(m & 3) * 64 + 4 * w + (m >> 2)];
  const bool  isg   = (m & 3) == 2;
  const float wdc = Wd[c], bdc = Bd[0];
  const float bqv = (w < 4) ? Bq[w * 16 + m] : 0.f;        // q-GEMM col bias
  const unsigned short* afp = afrag + (kh * 16) * 512 + c * 8;
  const int gb  = c & ~3;                                  // gate-group base lane
  const int col = 4 * w + (m >> 2);                        // owned logical column
  const int ci  = quad * 16 + 4 * (w & 3) + (m >> 2);      // sh_part read col
  const int wb  = w >> 2;                                  // sh_part read tile

  float cr[4] = {0.f, 0.f, 0.f, 0.f};                      // c-state, rows quad*4+r
  float o0 = 0.f, o1 = 0.f, o2 = 0.f, o3 = 0.f, o4 = 0.f, o5 = 0.f;  // Out stage
  float px = 0.f;                                          // X pair register

  // consumer byte-offset within a slot (chunk ch adds ch*4096)
  const uint32_t qoff = (uint32_t)((kh * 32 + (quad >> 1)) * 2048 +
                                   (nt * 16 + m) * 32 + (quad & 1) * 16);
  // producer byte-offset within a slot (block-major chunk)
  const uint32_t poff = (uint32_t)(blockIdx.x * 2048 + (w * 16 + m) * 32 + quad * 8);

  // ---- initial publish: q_0 = tanh(b_q) -> ring slot 0 ----
  if (w < 4) {
    unsigned short qb = f2bf(tanh_(bqv));
    uint32_t pp = (uint32_t)qb | ((uint32_t)qb << 16);
    unsigned long long v = (unsigned long long)pp | ((unsigned long long)pp << 32);
    unsigned long long* dst = (unsigned long long*)((char*)qRing + poff);
    __hip_atomic_store(dst, v, __ATOMIC_RELAXED, __HIP_MEMORY_SCOPE_AGENT);
    if (!ringfull) {
      asm volatile("s_waitcnt vmcnt(0)" ::: "memory");
      if (c == 0) {
        unsigned old = atomicAdd(cnt, 1u);
        if (old == 3u)
          __hip_atomic_store(&flags[blockIdx.x * 16], 1u,
                             __ATOMIC_RELAXED, __HIP_MEMORY_SCOPE_AGENT);
      }
    }
  }

  int slotR = 0;                                           // read slot for step t
  for (int t = 0; t < TT; ++t) {
    const int slotW = (slotR + 1 == rdepth) ? 0 : slotR + 1;

    // ---- X pair-read: full 128B line every other step ----
    if (((t & 1) == 0) && c < 32) {
      int tt = t + 1 + (c >> 4);                           // lanes 0-15: t+1; 16-31: t+2
      px = (tt < TT) ? X[(size_t)(base + w) * (TT * DD) + tt * DD + (c & 15)] : 0.f;
    }

    // ---- gates-GEMM (interleaved cols): D rows quad*4+r, phys col 16w+m ----
    f32x4 dg = {0.f, 0.f, 0.f, 0.f};
    {
      const unsigned short* ar = sh_hx + m * 104 + quad * 8;
      const unsigned short* br = whxT + (w * 16 + m) * 104 + quad * 8;
      #pragma unroll
      for (int ch = 0; ch < 3; ++ch)
        dg = __builtin_amdgcn_mfma_f32_16x16x32_bf16(*(const bf16x8*)(ar + ch * 32),
                                                     *(const bf16x8*)(br + ch * 32), dg, 0, 0, 0);
    }
    // per-lane activation (gate type = m&3; tanh only for gate 2) — no LDS
    float act[4];
    #pragma unroll
    for (int r = 0; r < 4; ++r) {
      float pa = dg[r] + bgate;
      float sg = sigmoid_(pa);
      float th = tanh_(pa);
      act[r] = isg ? th : sg;
    }

    // ---- q acquire: load all 16 once, then in-order validate/retry/MFMA ----
    const uint32_t sbase = (uint32_t)((size_t)slotR * (QSLOT_U32 * 4)) + qoff;
    u32x4 qv[16];
    f32x4 acc0 = {0.f,0.f,0.f,0.f}, acc1 = {0.f,0.f,0.f,0.f};
    if (ringfull) {
      #pragma unroll
      for (int ch = 0; ch < 16; ++ch) {
        uint32_t vo = sbase + (uint32_t)(ch * 4096);
        asm volatile("global_load_dwordx4 %0, %1, %2 sc0 sc1"
                     : "=v"(qv[ch]) : "v"(vo), "s"(qRing) : "memory");
      }
      asm volatile("s_waitcnt vmcnt(0)" ::: "memory");
      __builtin_amdgcn_sched_barrier(0);
      #pragma unroll
      for (int ch = 0; ch < 16; ch += 2) {
        // chunk ch -> acc0 (even chain)
        while (!__all((qv[ch][0] != SENT32) && (qv[ch][2] != SENT32))) {
          __builtin_amdgcn_s_sleep(1);
          uint32_t vo = sbase + (uint32_t)(ch * 4096);
          asm volatile("global_load_dwordx4 %0, %1, %2 sc0 sc1"
                       : "=v"(qv[ch]) : "v"(vo), "s"(qRing) : "memory");
          asm volatile("s_waitcnt vmcnt(0)" ::: "memory");
          __builtin_amdgcn_sched_barrier(0);
        }
        acc0 = __builtin_amdgcn_mfma_f32_16x16x32_bf16(
            *(const bf16x8*)(afp + ch * 512), asbf(qv[ch]), acc0, 0, 0, 0);
        // chunk ch+1 -> acc1 (odd chain)
        while (!__all((qv[ch + 1][0] != SENT32) && (qv[ch + 1][2] != SENT32))) {
          __builtin_amdgcn_s_sleep(1);
          uint32_t vo = sbase + (uint32_t)((ch + 1) * 4096);
          asm volatile("global_load_dwordx4 %0, %1, %2 sc0 sc1"
                       : "=v"(qv[ch + 1]) : "v"(vo), "s"(qRing) : "memory");
          asm volatile("s_waitcnt vmcnt(0)" ::: "memory");
          __builtin_amdgcn_sched_barrier(0);
        }
        acc1 = __builtin_amdgcn_mfma_f32_16x16x32_bf16(
            *(const bf16x8*)(afp + (ch + 1) * 512), asbf(qv[ch + 1]), acc1, 0, 0, 0);
      }
    } else {
      // fallback: flag wait + fence + plain loads
      const uint32_t target = (uint32_t)(t + 1);
      const int src = 32 * kh + (c & 31);
      for (;;) {
        uint32_t f = __hip_atomic_load(&flags[src * 16],
                                       __ATOMIC_RELAXED, __HIP_MEMORY_SCOPE_AGENT);
        if (__all((int)(f >= target))) break;
        __builtin_amdgcn_s_sleep(1);
      }
      __builtin_amdgcn_fence(__ATOMIC_ACQUIRE, "agent");
      #pragma unroll
      for (int ch = 0; ch < 16; ++ch)
        qv[ch] = *(const u32x4*)((char*)qRing + (size_t)sbase + (size_t)(ch * 4096));
      #pragma unroll
      for (int ch = 0; ch < 16; ch += 2) {
        acc0 = __builtin_amdgcn_mfma_f32_16x16x32_bf16(
            *(const bf16x8*)(afp + ch * 512), asbf(qv[ch]), acc0, 0, 0, 0);
        acc1 = __builtin_amdgcn_mfma_f32_16x16x32_bf16(
            *(const bf16x8*)(afp + (ch + 1) * 512), asbf(qv[ch + 1]), acc1, 0, 0, 0);
      }
    }
    sh_part[w * 65 + c] = acc0 + acc1;     // [16][65] padded stride
    __syncthreads();                       // B3: sh_part ready

    // reduce 4 K-quarters: thread needs rows quad*4+r at its logical col
    f32x4 vsum;
    {
      const f32x4* sp = sh_part;
      f32x4 p0 = sp[(0 * 4 + wb) * 65 + ci];
      f32x4 p1 = sp[(1 * 4 + wb) * 65 + ci];
      f32x4 p2 = sp[(2 * 4 + wb) * 65 + ci];
      f32x4 p3 = sp[(3 * 4 + wb) * 65 + ci];
      vsum = (p0 + p1) + (p2 + p3);
    }

    // ---- gather gates (intra-wave) + update 4 rows (x4 redundant) ----
    #pragma unroll
    for (int r = 0; r < 4; ++r) {
      float gi = __shfl(act[r], gb + 0);
      float gf = __shfl(act[r], gb + 1);
      float gg = __shfl(act[r], gb + 2);
      float go = __shfl(act[r], gb + 3);
      cr[r] = gf * (cr[r] + vsum[r]) + gi * gg;
      float h = go * tanh_(cr[r]);
      if ((m & 3) == 0) {                  // one writer per group
        shf32[(quad * 4 + r) * 65 + col] = h;
        sh_hx[(quad * 4 + r) * 104 + col] = f2bf(h);
      }
    }
    {
      float xw = (t & 1) ? __shfl(px, (c & 15) + 16) : px;
      if (c < 16) sh_hx[w * 104 + 64 + c] = f2bf(xw);
    }
    __syncthreads();                       // B4: h_t visible

    // ---- fused q-GEMM + publish into ring slot t+1 (block-major, 2KB) ----
    if (w < 4 && t < TT - 1) {
      f32x4 dq = {0.f, 0.f, 0.f, 0.f};
      const unsigned short* ar = sh_hx + m * 104 + quad * 8;
      const unsigned short* br = wqT + (w * 16 + m) * 72 + quad * 8;
      #pragma unroll
      for (int k2 = 0; k2 < 2; ++k2)
        dq = __builtin_amdgcn_mfma_f32_16x16x32_bf16(*(const bf16x8*)(ar + k2 * 32),
                                                     *(const bf16x8*)(br + k2 * 32), dq, 0, 0, 0);
      unsigned short b0 = f2bf(tanh_(dq[0] + bqv));
      unsigned short b1 = f2bf(tanh_(dq[1] + bqv));
      unsigned short b2 = f2bf(tanh_(dq[2] + bqv));
      unsigned short b3 = f2bf(tanh_(dq[3] + bqv));
      unsigned long long v =
          (unsigned long long)((uint32_t)b0 | ((uint32_t)b1 << 16)) |
          ((unsigned long long)((uint32_t)b2 | ((uint32_t)b3 << 16)) << 32);
      unsigned long long* dst = (unsigned long long*)
          ((char*)qRing + (size_t)slotW * (QSLOT_U32 * 4) + poff);
      __hip_atomic_store(dst, v, __ATOMIC_RELAXED, __HIP_MEMORY_SCOPE_AGENT);
      if (!ringfull) {
        asm volatile("s_waitcnt vmcnt(0)" ::: "memory");
        if (c == 0) {
          unsigned old = atomicAdd(cnt, 1u);
          if (old == (unsigned)(4 * t + 7))
            __hip_atomic_store(&flags[blockIdx.x * 16], (uint32_t)(t + 2),
                               __ATOMIC_RELAXED, __HIP_MEMORY_SCOPE_AGENT);
        }
      }
    }

    // ---- output projection -> register stage (f32 h from shf32) ----
    {
      float red = shf32[w * 65 + c] * wdc;
      #pragma unroll
      for (int off = 32; off; off >>= 1) red += __shfl_xor(red, off);
      float ov = red + bdc;                // every lane has the sum
      switch (t >> 6) {                    // static index (rule #20)
        case 0: if (c == (t & 63)) o0 = ov; break;
        case 1: if (c == (t & 63)) o1 = ov; break;
        case 2: if (c == (t & 63)) o2 = ov; break;
        case 3: if (c == (t & 63)) o3 = ov; break;
        case 4: if (c == (t & 63)) o4 = ov; break;
        default: if (c == (t & 63)) o5 = ov; break;
      }
    }

    slotR = slotW;
  }

  // ---- coalesced Out writeback: wave w owns row base+w ----
  {
    float* orow = Out + (size_t)(base + w) * TT;
    orow[c] = o0;
    orow[64 + c] = o1;
    orow[128 + c] = o2;
    orow[192 + c] = o3;
    orow[256 + c] = o4;
    if (320 + c < TT) orow[320 + c] = o5;
  }
}

extern "C" void kernel_launch(void* const* d_in, const int* in_sizes, int n_in,
                              void* d_out, int out_size, void* d_ws, size_t ws_size,
                              hipStream_t stream) {
  const float* X    = (const float*)d_in[0];
  const float* Af   = (const float*)d_in[1];
  const float* Wih  = (const float*)d_in[2];
  const float* Whh  = (const float*)d_in[3];
  const float* Bias = (const float*)d_in[4];
  const float* Wq   = (const float*)d_in[5];
  const float* Bq   = (const float*)d_in[6];
  const float* Wd   = (const float*)d_in[7];
  const float* Bd   = (const float*)d_in[8];
  float* Out = (float*)d_out;

  char* ws = (char*)d_ws;
  uint32_t* flags = (uint32_t*)ws;                         // 128 flags, 64B apart (8 KB)
  uint32_t* qRing = (uint32_t*)(ws + 8192);                // R slots x 256 KB

  long long avail = (long long)ws_size - 8192;
  int rdepth = (int)(avail / (QSLOT_U32 * 4));
  if (rdepth > TT + 1) rdepth = TT + 1;
  if (rdepth < 2) rdepth = 2;
  int ringfull = (rdepth >= TT + 1) ? 1 : 0;

  hipFuncSetAttribute((const void*)rgcn_persist,
                      hipFuncAttributeMaxDynamicSharedMemorySize, SMEM_BYTES);
  hipMemsetAsync(ws, 0, 8192, stream);                     // zero flags (poisoned 0xAA!)
  if (ringfull)                                            // sentinel-fill the ring
    hipMemsetAsync(qRing, 0xFF, (size_t)rdepth * QSLOT_U32 * 4, stream);
  hipLaunchKernelGGL(rgcn_persist, dim3(NBLK), dim3(NTHR), SMEM_BYTES, stream,
                     X, Af, Wih, Whh, Bias, Wq, Bq, Wd, Bd, Out, qRing, flags,
                     rdepth, ringfull);
}

// Round 9
// 2543.262 us; speedup vs baseline: 1.1306x; 1.1306x over previous
//
#include <hip/hip_runtime.h>
#include <stdint.h>

#define NN 2048
#define TT 365
#define DD 16
#define HH 64
#define NBLK 128      // 16 rows per block, 1 block/CU (LDS-bound)
#define NTHR 1024     // 16 waves
#define SMEM_BYTES 152192
#define QSLOT_U32 65536          // 256 KB per ring slot: [128 blocks][2KB chunk]
#define SENT32 0xFFFFFFFFu       // bf16 NaN pair: unreachable for tanh output

typedef __attribute__((ext_vector_type(8))) short bf16x8;
typedef __attribute__((ext_vector_type(4))) float f32x4;
typedef __attribute__((ext_vector_type(4))) unsigned int u32x4;

__device__ __forceinline__ unsigned short f2bf(float f) {
  union { float f; uint32_t u; } z; z.f = f;
  uint32_t r = z.u + 0x7fffu + ((z.u >> 16) & 1u);
  return (unsigned short)(r >> 16);
}
__device__ __forceinline__ float sigmoid_(float x) { return 1.f / (1.f + __expf(-x)); }
__device__ __forceinline__ float tanh_(float x) {
  float ax = fabsf(x);
  float e = __expf(-2.f * ax);
  float r = (1.f - e) / (1.f + e);
  return x < 0.f ? -r : r;
}
__device__ __forceinline__ bf16x8 asbf(u32x4 v) { return __builtin_bit_cast(bf16x8, v); }

// R22 = R20's q-acquire (batch load + batch pend-mask retry: all pending
// chunks reloaded concurrently in ONE round trip — R21's in-order per-chunk
// retry head-of-line-blocked on the slowest of 16 source blocks, +690us)
//    + R21's gate-interleave epilogue (all 4 gates of a logical col in 4
// adjacent lanes -> intra-wave shfl; B1/B2 barriers + sh_g LDS round trip
// deleted; bank conflicts 3.3e7 -> 2.1e7 verified in R21).
// Everything else = R20: block-major ring (slot=[128 blk][2KB], contiguous
// full-line publish), reg-staged Out (coalesced writeback at end), X
// pair-read (full 128B line every other step), flag-free sentinel ring
// (write-once 366 slots), sc0sc1 bypass loads issued AT acquire.
__global__ __launch_bounds__(NTHR) __attribute__((amdgpu_waves_per_eu(4, 4)))
void rgcn_persist(
    const float* __restrict__ X, const float* __restrict__ Af,
    const float* __restrict__ Wih, const float* __restrict__ Whh,
    const float* __restrict__ Bias, const float* __restrict__ Wq,
    const float* __restrict__ Bq, const float* __restrict__ Wd,
    const float* __restrict__ Bd, float* __restrict__ Out,
    uint32_t* qRing, uint32_t* flags, int rdepth, int ringfull)
{
  extern __shared__ __align__(16) char smem[];
  unsigned short* afrag = (unsigned short*)smem;                 // [64kc][64ln][8] 65536
  unsigned short* whxT  = (unsigned short*)(smem + 65536);       // [256n][104k]    53248
  unsigned short* wqT   = (unsigned short*)(smem + 118784);      // [64n][72k]       9216
  f32x4*          sh_part = (f32x4*)(smem + 128000);             // [16][65] f32x4  16640
  float*          shf32 = (float*)(smem + 144640);               // [16][65] f32 h   4160
  unsigned short* sh_hx = (unsigned short*)(smem + 148800);      // [16][104] bf16   3328
  unsigned int*   cnt   = (unsigned int*)(smem + 152128);        // fallback arrival ctr

  const int tid = threadIdx.x;
  const int w = tid >> 6;        // wave 0..15
  const int c = tid & 63;        // lane
  const int base = blockIdx.x * 16;
  const int m = c & 15, quad = c >> 4;
  const int nt = w & 3, kh = w >> 2;                       // phase B tile coords

  // ---- one-time staging ----
  for (int i = tid; i < 256 * 104; i += NTHR) {            // [WhhT|WihT|0], gate-interleaved
    int n = i / 104, k = i - n * 104;                      // n = PHYSICAL col
    int src = (n & 3) * 64 + (n >> 2);                     // logical source col
    float v = (k < 64) ? Whh[k * 256 + src] : (k < 80) ? Wih[(k - 64) * 256 + src] : 0.f;
    whxT[i] = f2bf(v);
  }
  for (int i = tid; i < 64 * 72; i += NTHR) {              // WqT (pad k 64..71 = 0)
    int n = i / 72, k = i - n * 72;
    wqT[i] = (k < 64) ? f2bf(Wq[k * 64 + n]) : (unsigned short)0;
  }
  for (int i = tid; i < 16 * NN; i += NTHR) {              // A -> MFMA A-frag layout
    int r = i >> 11, k = i & (NN - 1);
    afrag[(k >> 5) * 512 + (((k >> 3) & 3) * 16 + r) * 8 + (k & 7)] =
        f2bf(Af[(size_t)(base + r) * NN + k]);
  }
  for (int i = tid; i < 16 * 104; i += NTHR) sh_hx[i] = 0; // h=0, x below, pad=0
  __syncthreads();
  if (c < 16) sh_hx[w * 104 + 64 + c] = f2bf(X[(size_t)(base + w) * (TT * DD) + c]);
  if (tid == 0) *cnt = 0u;
  __syncthreads();

  // per-lane gate constants (interleaved layout): phys col p = 16w+m
  const float bgate = Bias[(m & 3) * 64 + 4 * w + (m >> 2)];
  const bool  isg   = (m & 3) == 2;
  const float wdc = Wd[c], bdc = Bd[0];
  const float bqv = (w < 4) ? Bq[w * 16 + m] : 0.f;        // q-GEMM col bias
  const unsigned short* afp = afrag + (kh * 16) * 512 + c * 8;
  const int gb  = c & ~3;                                  // gate-group base lane
  const int col = 4 * w + (m >> 2);                        // owned logical column
  const int ci  = quad * 16 + 4 * (w & 3) + (m >> 2);      // sh_part read col
  const int wb  = w >> 2;                                  // sh_part read tile

  float cr[4] = {0.f, 0.f, 0.f, 0.f};                      // c-state, rows quad*4+r
  float o0 = 0.f, o1 = 0.f, o2 = 0.f, o3 = 0.f, o4 = 0.f, o5 = 0.f;  // Out stage
  float px = 0.f;                                          // X pair register

  // consumer byte-offset within a slot (chunk ch adds ch*4096)
  const uint32_t qoff = (uint32_t)((kh * 32 + (quad >> 1)) * 2048 +
                                   (nt * 16 + m) * 32 + (quad & 1) * 16);
  // producer byte-offset within a slot (block-major chunk)
  const uint32_t poff = (uint32_t)(blockIdx.x * 2048 + (w * 16 + m) * 32 + quad * 8);

  // ---- initial publish: q_0 = tanh(b_q) -> ring slot 0 ----
  if (w < 4) {
    unsigned short qb = f2bf(tanh_(bqv));
    uint32_t pp = (uint32_t)qb | ((uint32_t)qb << 16);
    unsigned long long v = (unsigned long long)pp | ((unsigned long long)pp << 32);
    unsigned long long* dst = (unsigned long long*)((char*)qRing + poff);
    __hip_atomic_store(dst, v, __ATOMIC_RELAXED, __HIP_MEMORY_SCOPE_AGENT);
    if (!ringfull) {
      asm volatile("s_waitcnt vmcnt(0)" ::: "memory");
      if (c == 0) {
        unsigned old = atomicAdd(cnt, 1u);
        if (old == 3u)
          __hip_atomic_store(&flags[blockIdx.x * 16], 1u,
                             __ATOMIC_RELAXED, __HIP_MEMORY_SCOPE_AGENT);
      }
    }
  }

  int slotR = 0;                                           // read slot for step t
  for (int t = 0; t < TT; ++t) {
    const int slotW = (slotR + 1 == rdepth) ? 0 : slotR + 1;

    // ---- X pair-read: full 128B line every other step ----
    if (((t & 1) == 0) && c < 32) {
      int tt = t + 1 + (c >> 4);                           // lanes 0-15: t+1; 16-31: t+2
      px = (tt < TT) ? X[(size_t)(base + w) * (TT * DD) + tt * DD + (c & 15)] : 0.f;
    }

    // ---- gates-GEMM (interleaved cols): D rows quad*4+r, phys col 16w+m ----
    f32x4 dg = {0.f, 0.f, 0.f, 0.f};
    {
      const unsigned short* ar = sh_hx + m * 104 + quad * 8;
      const unsigned short* br = whxT + (w * 16 + m) * 104 + quad * 8;
      #pragma unroll
      for (int ch = 0; ch < 3; ++ch)
        dg = __builtin_amdgcn_mfma_f32_16x16x32_bf16(*(const bf16x8*)(ar + ch * 32),
                                                     *(const bf16x8*)(br + ch * 32), dg, 0, 0, 0);
    }
    // per-lane activation (gate type = m&3; tanh only for gate 2) — no LDS
    float act[4];
    #pragma unroll
    for (int r = 0; r < 4; ++r) {
      float pa = dg[r] + bgate;
      float sg = sigmoid_(pa);
      float th = tanh_(pa);
      act[r] = isg ? th : sg;
    }

    // ---- q acquire (R20 batch structure: issue AT acquire, batch retry) ----
    const uint64_t qa =
        (uint64_t)((char*)qRing + (size_t)slotR * (QSLOT_U32 * 4) + qoff);
    u32x4 qv[16];
    if (ringfull) {
      // flag-free: sentinel-verified L3-direct loads; retry pending only
      unsigned pend = 0xFFFFu;
      int pass = 0;
      do {
        if (pass) __builtin_amdgcn_s_sleep(1);             // backoff
        #pragma unroll
        for (int ch = 0; ch < 16; ++ch)
          if (pend & (1u << ch))
            asm volatile("global_load_dwordx4 %0, %1, off sc0 sc1"
                         : "=v"(qv[ch]) : "v"(qa + (uint64_t)(ch * 4096)) : "memory");
        asm volatile("s_waitcnt vmcnt(0)" ::: "memory");
        __builtin_amdgcn_sched_barrier(0);
        #pragma unroll
        for (int ch = 0; ch < 16; ++ch)
          if (pend & (1u << ch))
            if (qv[ch][0] != SENT32 && qv[ch][2] != SENT32)  // two 8B atomic halves
              pend &= ~(1u << ch);
        pass = 1;
      } while (!__all(pend == 0));
    } else {
      // fallback: flag wait + fence + plain loads
      const uint32_t target = (uint32_t)(t + 1);
      const int src = 32 * kh + (c & 31);
      for (;;) {
        uint32_t f = __hip_atomic_load(&flags[src * 16],
                                       __ATOMIC_RELAXED, __HIP_MEMORY_SCOPE_AGENT);
        if (__all((int)(f >= target))) break;
        __builtin_amdgcn_s_sleep(1);
      }
      __builtin_amdgcn_fence(__ATOMIC_ACQUIRE, "agent");
      #pragma unroll
      for (int ch = 0; ch < 16; ++ch)
        qv[ch] = *(const u32x4*)(qa + (uint64_t)(ch * 4096));
    }

    // ---- phase B: Aq_t via MFMA (dual chain) ----
    f32x4 acc0 = {0.f,0.f,0.f,0.f}, acc1 = {0.f,0.f,0.f,0.f};
    #pragma unroll
    for (int ch = 0; ch < 16; ch += 2) {
      acc0 = __builtin_amdgcn_mfma_f32_16x16x32_bf16(
          *(const bf16x8*)(afp + ch * 512), asbf(qv[ch]), acc0, 0, 0, 0);
      acc1 = __builtin_amdgcn_mfma_f32_16x16x32_bf16(
          *(const bf16x8*)(afp + (ch + 1) * 512), asbf(qv[ch + 1]), acc1, 0, 0, 0);
    }
    sh_part[w * 65 + c] = acc0 + acc1;     // [16][65] padded stride
    __syncthreads();                       // B3: sh_part ready

    // reduce 4 K-quarters: thread needs rows quad*4+r at its logical col
    f32x4 vsum;
    {
      const f32x4* sp = sh_part;
      f32x4 p0 = sp[(0 * 4 + wb) * 65 + ci];
      f32x4 p1 = sp[(1 * 4 + wb) * 65 + ci];
      f32x4 p2 = sp[(2 * 4 + wb) * 65 + ci];
      f32x4 p3 = sp[(3 * 4 + wb) * 65 + ci];
      vsum = (p0 + p1) + (p2 + p3);
    }

    // ---- gather gates (intra-wave) + update 4 rows (x4 redundant) ----
    #pragma unroll
    for (int r = 0; r < 4; ++r) {
      float gi = __shfl(act[r], gb + 0);
      float gf = __shfl(act[r], gb + 1);
      float gg = __shfl(act[r], gb + 2);
      float go = __shfl(act[r], gb + 3);
      cr[r] = gf * (cr[r] + vsum[r]) + gi * gg;
      float h = go * tanh_(cr[r]);
      if ((m & 3) == 0) {                  // one writer per group
        shf32[(quad * 4 + r) * 65 + col] = h;
        sh_hx[(quad * 4 + r) * 104 + col] = f2bf(h);
      }
    }
    {
      float xw = (t & 1) ? __shfl(px, (c & 15) + 16) : px;
      if (c < 16) sh_hx[w * 104 + 64 + c] = f2bf(xw);
    }
    __syncthreads();                       // B4: h_t visible

    // ---- fused q-GEMM + publish into ring slot t+1 (block-major, 2KB) ----
    if (w < 4 && t < TT - 1) {
      f32x4 dq = {0.f, 0.f, 0.f, 0.f};
      const unsigned short* ar = sh_hx + m * 104 + quad * 8;
      const unsigned short* br = wqT + (w * 16 + m) * 72 + quad * 8;
      #pragma unroll
      for (int k2 = 0; k2 < 2; ++k2)
        dq = __builtin_amdgcn_mfma_f32_16x16x32_bf16(*(const bf16x8*)(ar + k2 * 32),
                                                     *(const bf16x8*)(br + k2 * 32), dq, 0, 0, 0);
      unsigned short b0 = f2bf(tanh_(dq[0] + bqv));
      unsigned short b1 = f2bf(tanh_(dq[1] + bqv));
      unsigned short b2 = f2bf(tanh_(dq[2] + bqv));
      unsigned short b3 = f2bf(tanh_(dq[3] + bqv));
      unsigned long long v =
          (unsigned long long)((uint32_t)b0 | ((uint32_t)b1 << 16)) |
          ((unsigned long long)((uint32_t)b2 | ((uint32_t)b3 << 16)) << 32);
      unsigned long long* dst = (unsigned long long*)
          ((char*)qRing + (size_t)slotW * (QSLOT_U32 * 4) + poff);
      __hip_atomic_store(dst, v, __ATOMIC_RELAXED, __HIP_MEMORY_SCOPE_AGENT);
      if (!ringfull) {
        asm volatile("s_waitcnt vmcnt(0)" ::: "memory");
        if (c == 0) {
          unsigned old = atomicAdd(cnt, 1u);
          if (old == (unsigned)(4 * t + 7))
            __hip_atomic_store(&flags[blockIdx.x * 16], (uint32_t)(t + 2),
                               __ATOMIC_RELAXED, __HIP_MEMORY_SCOPE_AGENT);
        }
      }
    }

    // ---- output projection -> register stage (f32 h from shf32) ----
    {
      float red = shf32[w * 65 + c] * wdc;
      #pragma unroll
      for (int off = 32; off; off >>= 1) red += __shfl_xor(red, off);
      float ov = red + bdc;                // every lane has the sum
      switch (t >> 6) {                    // static index (rule #20)
        case 0: if (c == (t & 63)) o0 = ov; break;
        case 1: if (c == (t & 63)) o1 = ov; break;
        case 2: if (c == (t & 63)) o2 = ov; break;
        case 3: if (c == (t & 63)) o3 = ov; break;
        case 4: if (c == (t & 63)) o4 = ov; break;
        default: if (c == (t & 63)) o5 = ov; break;
      }
    }

    slotR = slotW;
  }

  // ---- coalesced Out writeback: wave w owns row base+w ----
  {
    float* orow = Out + (size_t)(base + w) * TT;
    orow[c] = o0;
    orow[64 + c] = o1;
    orow[128 + c] = o2;
    orow[192 + c] = o3;
    orow[256 + c] = o4;
    if (320 + c < TT) orow[320 + c] = o5;
  }
}

extern "C" void kernel_launch(void* const* d_in, const int* in_sizes, int n_in,
                              void* d_out, int out_size, void* d_ws, size_t ws_size,
                              hipStream_t stream) {
  const float* X    = (const float*)d_in[0];
  const float* Af   = (const float*)d_in[1];
  const float* Wih  = (const float*)d_in[2];
  const float* Whh  = (const float*)d_in[3];
  const float* Bias = (const float*)d_in[4];
  const float* Wq   = (const float*)d_in[5];
  const float* Bq   = (const float*)d_in[6];
  const float* Wd   = (const float*)d_in[7];
  const float* Bd   = (const float*)d_in[8];
  float* Out = (float*)d_out;

  char* ws = (char*)d_ws;
  uint32_t* flags = (uint32_t*)ws;                         // 128 flags, 64B apart (8 KB)
  uint32_t* qRing = (uint32_t*)(ws + 8192);                // R slots x 256 KB

  long long avail = (long long)ws_size - 8192;
  int rdepth = (int)(avail / (QSLOT_U32 * 4));
  if (rdepth > TT + 1) rdepth = TT + 1;
  if (rdepth < 2) rdepth = 2;
  int ringfull = (rdepth >= TT + 1) ? 1 : 0;

  hipFuncSetAttribute((const void*)rgcn_persist,
                      hipFuncAttributeMaxDynamicSharedMemorySize, SMEM_BYTES);
  hipMemsetAsync(ws, 0, 8192, stream);                     // zero flags (poisoned 0xAA!)
  if (ringfull)                                            // sentinel-fill the ring
    hipMemsetAsync(qRing, 0xFF, (size_t)rdepth * QSLOT_U32 * 4, stream);
  hipLaunchKernelGGL(rgcn_persist, dim3(NBLK), dim3(NTHR), SMEM_BYTES, stream,
                     X, Af, Wih, Whh, Bias, Wq, Bq, Wd, Bd, Out, qRing, flags,
                     rdepth, ringfull);
}

// Round 10
// 2129.805 us; speedup vs baseline: 1.3501x; 1.1941x over previous
//
#include <hip/hip_runtime.h>
#include <stdint.h>

#define NN 2048
#define TT 365
#define DD 16
#define HH 64
#define NBLK 128      // 16 rows per block, 1 block/CU (LDS-bound)
#define NTHR 1024     // 16 waves
#define SMEM_BYTES 150016
#define QSLOT_U32 65536          // 256 KB per ring slot: [128 blocks][2KB chunk]
#define SENT32 0xFFFFFFFFu       // bf16 NaN pair: unreachable for tanh output

typedef __attribute__((ext_vector_type(8))) short bf16x8;
typedef __attribute__((ext_vector_type(4))) float f32x4;
typedef __attribute__((ext_vector_type(4))) unsigned int u32x4;

__device__ __forceinline__ unsigned short f2bf(float f) {
  union { float f; uint32_t u; } z; z.f = f;
  uint32_t r = z.u + 0x7fffu + ((z.u >> 16) & 1u);
  return (unsigned short)(r >> 16);
}
__device__ __forceinline__ float sigmoid_(float x) { return 1.f / (1.f + __expf(-x)); }
__device__ __forceinline__ float tanh_(float x) {
  float ax = fabsf(x);
  float e = __expf(-2.f * ax);
  float r = (1.f - e) / (1.f + e);
  return x < 0.f ? -r : r;
}
__device__ __forceinline__ bf16x8 asbf(u32x4 v) { return __builtin_bit_cast(bf16x8, v); }

// R23 = exact R20 (best @2185us: block-major ring, sh_g epilogue, reg-staged
// Out, X pair-read, flag-free sentinel ring) + ONE change:
//   q acquire first pass uses PLAIN CACHED loads (L1/L2): the 16 blocks on an
//   XCD read the same 256KB slot, so 15/16 of chunk reads become L2 hits
//   (~200cy) instead of L3-bypass round trips (~700cy), and L3 request
//   traffic drops from 32MB/step toward ~2MB/step. Retries for pending
//   (sentinel) chunks stay sc0sc1 BYPASS — bypass always sees L3 truth, so a
//   stale-cached sentinel line cannot deadlock; it just falls to the retry
//   path (which is what every chunk did before). Loads still issued AT
//   acquire, never early (early cached touches would poison L2 with
//   pre-publish sentinel lines for the whole XCD — sharpened R18 lesson).
// R22 lesson folded in: gate-interleave reverted (redundant transcendentals
// on the serial path cost more than the 2 barriers it saved).
__global__ __launch_bounds__(NTHR) __attribute__((amdgpu_waves_per_eu(4, 4)))
void rgcn_persist(
    const float* __restrict__ X, const float* __restrict__ Af,
    const float* __restrict__ Wih, const float* __restrict__ Whh,
    const float* __restrict__ Bias, const float* __restrict__ Wq,
    const float* __restrict__ Bq, const float* __restrict__ Wd,
    const float* __restrict__ Bd, float* __restrict__ Out,
    uint32_t* qRing, uint32_t* flags, int rdepth, int ringfull)
{
  extern __shared__ __align__(16) char smem[];
  unsigned short* afrag = (unsigned short*)smem;                 // [64kc][64ln][8] 65536
  unsigned short* whxT  = (unsigned short*)(smem + 65536);       // [256n][104k]    53248
  unsigned short* wqT   = (unsigned short*)(smem + 118784);      // [64n][72k]       9216
  float*          sh_g  = (float*)(smem + 128000);               // [16][260] fp32  16640
  f32x4*          sh_part = (f32x4*)(smem + 128000);             // union [16][65] 16640
  unsigned short* sh_hx = (unsigned short*)(smem + 144640);      // [16][104] bf16   3328
  unsigned int*   cnt   = (unsigned int*)(smem + 147968);        // fallback arrival ctr

  const int tid = threadIdx.x;
  const int w = tid >> 6;        // wave 0..15 (== node row for per-thread work)
  const int c = tid & 63;        // lane
  const int base = blockIdx.x * 16;
  const int m = c & 15, quad = c >> 4;
  const int nt = w & 3, kh = w >> 2;                       // phase B tile coords

  // ---- one-time staging ----
  for (int i = tid; i < 256 * 104; i += NTHR) {            // [WhhT | WihT | 0]
    int n = i / 104, k = i - n * 104;
    float v = (k < 64) ? Whh[k * 256 + n] : (k < 80) ? Wih[(k - 64) * 256 + n] : 0.f;
    whxT[i] = f2bf(v);
  }
  for (int i = tid; i < 64 * 72; i += NTHR) {              // WqT (pad k 64..71 = 0)
    int n = i / 72, k = i - n * 72;
    wqT[i] = (k < 64) ? f2bf(Wq[k * 64 + n]) : (unsigned short)0;
  }
  for (int i = tid; i < 16 * NN; i += NTHR) {              // A -> MFMA A-frag layout
    int r = i >> 11, k = i & (NN - 1);
    afrag[(k >> 5) * 512 + (((k >> 3) & 3) * 16 + r) * 8 + (k & 7)] =
        f2bf(Af[(size_t)(base + r) * NN + k]);
  }
  for (int i = tid; i < 16 * 104; i += NTHR) sh_hx[i] = 0; // h=0, x below, pad=0
  __syncthreads();
  if (c < 16) sh_hx[w * 104 + 64 + c] = f2bf(X[(size_t)(base + w) * (TT * DD) + c]);
  if (tid == 0) *cnt = 0u;
  __syncthreads();

  const float b_i = Bias[c], b_f = Bias[64 + c], b_g = Bias[128 + c], b_o = Bias[192 + c];
  const float wdc = Wd[c], bdc = Bd[0];
  const float bqv = (w < 4) ? Bq[w * 16 + m] : 0.f;        // q-GEMM col bias
  const unsigned short* afp = afrag + (kh * 16) * 512 + c * 8;

  float creg = 0.f, hreg = 0.f;
  float o0 = 0.f, o1 = 0.f, o2 = 0.f, o3 = 0.f, o4 = 0.f, o5 = 0.f;  // Out stage
  float px = 0.f;                                          // X pair register

  // consumer byte-offset within a slot (chunk ch adds ch*4096)
  const uint32_t qoff = (uint32_t)((kh * 32 + (quad >> 1)) * 2048 +
                                   (nt * 16 + m) * 32 + (quad & 1) * 16);
  // producer byte-offset within a slot (block-major chunk)
  const uint32_t poff = (uint32_t)(blockIdx.x * 2048 + (w * 16 + m) * 32 + quad * 8);

  // ---- initial publish: q_0 = tanh(b_q) -> ring slot 0 ----
  if (w < 4) {
    unsigned short qb = f2bf(tanh_(bqv));
    uint32_t pp = (uint32_t)qb | ((uint32_t)qb << 16);
    unsigned long long v = (unsigned long long)pp | ((unsigned long long)pp << 32);
    unsigned long long* dst = (unsigned long long*)((char*)qRing + poff);
    __hip_atomic_store(dst, v, __ATOMIC_RELAXED, __HIP_MEMORY_SCOPE_AGENT);
    if (!ringfull) {
      asm volatile("s_waitcnt vmcnt(0)" ::: "memory");
      if (c == 0) {
        unsigned old = atomicAdd(cnt, 1u);
        if (old == 3u)
          __hip_atomic_store(&flags[blockIdx.x * 16], 1u,
                             __ATOMIC_RELAXED, __HIP_MEMORY_SCOPE_AGENT);
      }
    }
  }

  int slotR = 0;                                           // read slot for step t
  for (int t = 0; t < TT; ++t) {
    const int slotW = (slotR + 1 == rdepth) ? 0 : slotR + 1;

    // ---- X pair-read: full 128B line every other step ----
    if (((t & 1) == 0) && c < 32) {
      int tt = t + 1 + (c >> 4);                           // lanes 0-15: t+1; 16-31: t+2
      px = (tt < TT) ? X[(size_t)(base + w) * (TT * DD) + tt * DD + (c & 15)] : 0.f;
    }

    f32x4 dg = {0.f, 0.f, 0.f, 0.f};       // gates-GEMM
    {
      const unsigned short* ar = sh_hx + m * 104 + quad * 8;
      const unsigned short* br = whxT + (w * 16 + m) * 104 + quad * 8;
      #pragma unroll
      for (int ch = 0; ch < 3; ++ch)
        dg = __builtin_amdgcn_mfma_f32_16x16x32_bf16(*(const bf16x8*)(ar + ch * 32),
                                                     *(const bf16x8*)(br + ch * 32), dg, 0, 0, 0);
    }
    #pragma unroll
    for (int r = 0; r < 4; ++r)            // D: row=quad*4+r, col=16w+m
      sh_g[(quad * 4 + r) * 260 + w * 16 + m] = dg[r];
    __syncthreads();                       // B1: sh_g ready

    float gi = sigmoid_(b_i + sh_g[w * 260 + c]);
    float gf = sigmoid_(b_f + sh_g[w * 260 + 64 + c]);
    float gg = tanh_  (b_g + sh_g[w * 260 + 128 + c]);
    float go = sigmoid_(b_o + sh_g[w * 260 + 192 + c]);
    __syncthreads();                       // B2: sh_g free for sh_part reuse

    // ---- q acquire: pass 0 = CACHED loads (L2-shared across XCD);
    //      retries = sc0sc1 BYPASS for pending chunks only (no deadlock) ----
    const uint64_t qa =
        (uint64_t)((char*)qRing + (size_t)slotR * (QSLOT_U32 * 4) + qoff);
    u32x4 qv[16];
    if (ringfull) {
      unsigned pend = 0xFFFFu;
      #pragma unroll
      for (int ch = 0; ch < 16; ++ch)                      // cached first pass
        asm volatile("global_load_dwordx4 %0, %1, off"
                     : "=v"(qv[ch]) : "v"(qa + (uint64_t)(ch * 4096)) : "memory");
      asm volatile("s_waitcnt vmcnt(0)" ::: "memory");
      __builtin_amdgcn_sched_barrier(0);
      #pragma unroll
      for (int ch = 0; ch < 16; ++ch)
        if (qv[ch][0] != SENT32 && qv[ch][2] != SENT32)    // two 8B atomic halves
          pend &= ~(1u << ch);
      while (!__all(pend == 0)) {
        __builtin_amdgcn_s_sleep(1);                       // backoff
        #pragma unroll
        for (int ch = 0; ch < 16; ++ch)
          if (pend & (1u << ch))                           // bypass retry, pending only
            asm volatile("global_load_dwordx4 %0, %1, off sc0 sc1"
                         : "=v"(qv[ch]) : "v"(qa + (uint64_t)(ch * 4096)) : "memory");
        asm volatile("s_waitcnt vmcnt(0)" ::: "memory");
        __builtin_amdgcn_sched_barrier(0);
        #pragma unroll
        for (int ch = 0; ch < 16; ++ch)
          if (pend & (1u << ch))
            if (qv[ch][0] != SENT32 && qv[ch][2] != SENT32)
              pend &= ~(1u << ch);
      }
    } else {
      // fallback: flag wait + fence + plain loads
      const uint32_t target = (uint32_t)(t + 1);
      const int src = 32 * kh + (c & 31);
      for (;;) {
        uint32_t f = __hip_atomic_load(&flags[src * 16],
                                       __ATOMIC_RELAXED, __HIP_MEMORY_SCOPE_AGENT);
        if (__all((int)(f >= target))) break;
        __builtin_amdgcn_s_sleep(1);
      }
      __builtin_amdgcn_fence(__ATOMIC_ACQUIRE, "agent");
      #pragma unroll
      for (int ch = 0; ch < 16; ++ch)
        qv[ch] = *(const u32x4*)(qa + (uint64_t)(ch * 4096));
    }

    // ---- phase B: Aq_t via MFMA (dual chain) ----
    f32x4 acc0 = {0.f,0.f,0.f,0.f}, acc1 = {0.f,0.f,0.f,0.f};
    #pragma unroll
    for (int ch = 0; ch < 16; ch += 2) {
      acc0 = __builtin_amdgcn_mfma_f32_16x16x32_bf16(
          *(const bf16x8*)(afp + ch * 512), asbf(qv[ch]), acc0, 0, 0, 0);
      acc1 = __builtin_amdgcn_mfma_f32_16x16x32_bf16(
          *(const bf16x8*)(afp + (ch + 1) * 512), asbf(qv[ch + 1]), acc1, 0, 0, 0);
    }
    sh_part[w * 65 + c] = acc0 + acc1;     // [16][65] padded stride
    __syncthreads();                       // B3

    // conflict-free reduce: broadcast b128 reads, vector sum, uniform select
    f32x4 vs;
    {
      const f32x4* sp = sh_part;
      const int li = (w >> 2) * 16 + m;
      f32x4 p0 = sp[(0 * 4 + quad) * 65 + li];
      f32x4 p1 = sp[(1 * 4 + quad) * 65 + li];
      f32x4 p2 = sp[(2 * 4 + quad) * 65 + li];
      f32x4 p3 = sp[(3 * 4 + quad) * 65 + li];
      vs = (p0 + p1) + (p2 + p3);
    }
    float a01 = (w & 1) ? vs[1] : vs[0];
    float a23 = (w & 1) ? vs[3] : vs[2];
    float aqv = (w & 2) ? a23 : a01;

    // ---- update ----
    creg = gf * (creg + aqv) + gi * gg;
    hreg = go * tanh_(creg);
    sh_hx[w * 104 + c] = f2bf(hreg);
    {
      float xw = (t & 1) ? __shfl(px, (c & 15) + 16) : px;
      if (c < 16) sh_hx[w * 104 + 64 + c] = f2bf(xw);
    }
    __syncthreads();                       // B4: h_t visible

    // ---- fused q-GEMM + publish into ring slot t+1 (block-major, 2KB) ----
    if (w < 4 && t < TT - 1) {
      f32x4 dq = {0.f, 0.f, 0.f, 0.f};
      const unsigned short* ar = sh_hx + m * 104 + quad * 8;
      const unsigned short* br = wqT + (w * 16 + m) * 72 + quad * 8;
      #pragma unroll
      for (int k2 = 0; k2 < 2; ++k2)
        dq = __builtin_amdgcn_mfma_f32_16x16x32_bf16(*(const bf16x8*)(ar + k2 * 32),
                                                     *(const bf16x8*)(br + k2 * 32), dq, 0, 0, 0);
      // D: row=quad*4+r (node), col=16w+m -> 4 consecutive nodes = one 8B store
      unsigned short b0 = f2bf(tanh_(dq[0] + bqv));
      unsigned short b1 = f2bf(tanh_(dq[1] + bqv));
      unsigned short b2 = f2bf(tanh_(dq[2] + bqv));
      unsigned short b3 = f2bf(tanh_(dq[3] + bqv));
      unsigned long long v =
          (unsigned long long)((uint32_t)b0 | ((uint32_t)b1 << 16)) |
          ((unsigned long long)((uint32_t)b2 | ((uint32_t)b3 << 16)) << 32);
      unsigned long long* dst = (unsigned long long*)
          ((char*)qRing + (size_t)slotW * (QSLOT_U32 * 4) + poff);
      __hip_atomic_store(dst, v, __ATOMIC_RELAXED, __HIP_MEMORY_SCOPE_AGENT);
      if (!ringfull) {
        asm volatile("s_waitcnt vmcnt(0)" ::: "memory");
        if (c == 0) {
          unsigned old = atomicAdd(cnt, 1u);
          if (old == (unsigned)(4 * t + 7))
            __hip_atomic_store(&flags[blockIdx.x * 16], (uint32_t)(t + 2),
                               __ATOMIC_RELAXED, __HIP_MEMORY_SCOPE_AGENT);
        }
      }
    }

    // ---- output projection -> REGISTER stage (no per-step global store) ----
    {
      float red = hreg * wdc;
      #pragma unroll
      for (int off = 32; off; off >>= 1) red += __shfl_xor(red, off);
      float ov = red + bdc;                // every lane has the sum
      switch (t >> 6) {                    // static index (rule #20)
        case 0: if (c == (t & 63)) o0 = ov; break;
        case 1: if (c == (t & 63)) o1 = ov; break;
        case 2: if (c == (t & 63)) o2 = ov; break;
        case 3: if (c == (t & 63)) o3 = ov; break;
        case 4: if (c == (t & 63)) o4 = ov; break;
        default: if (c == (t & 63)) o5 = ov; break;
      }
    }

    slotR = slotW;
  }

  // ---- coalesced Out writeback: wave w owns row base+w ----
  {
    float* orow = Out + (size_t)(base + w) * TT;
    orow[c] = o0;
    orow[64 + c] = o1;
    orow[128 + c] = o2;
    orow[192 + c] = o3;
    orow[256 + c] = o4;
    if (320 + c < TT) orow[320 + c] = o5;
  }
}

extern "C" void kernel_launch(void* const* d_in, const int* in_sizes, int n_in,
                              void* d_out, int out_size, void* d_ws, size_t ws_size,
                              hipStream_t stream) {
  const float* X    = (const float*)d_in[0];
  const float* Af   = (const float*)d_in[1];
  const float* Wih  = (const float*)d_in[2];
  const float* Whh  = (const float*)d_in[3];
  const float* Bias = (const float*)d_in[4];
  const float* Wq   = (const float*)d_in[5];
  const float* Bq   = (const float*)d_in[6];
  const float* Wd   = (const float*)d_in[7];
  const float* Bd   = (const float*)d_in[8];
  float* Out = (float*)d_out;

  char* ws = (char*)d_ws;
  uint32_t* flags = (uint32_t*)ws;                         // 128 flags, 64B apart (8 KB)
  uint32_t* qRing = (uint32_t*)(ws + 8192);                // R slots x 256 KB

  long long avail = (long long)ws_size - 8192;
  int rdepth = (int)(avail / (QSLOT_U32 * 4));
  if (rdepth > TT + 1) rdepth = TT + 1;
  if (rdepth < 2) rdepth = 2;
  int ringfull = (rdepth >= TT + 1) ? 1 : 0;

  hipFuncSetAttribute((const void*)rgcn_persist,
                      hipFuncAttributeMaxDynamicSharedMemorySize, SMEM_BYTES);
  hipMemsetAsync(ws, 0, 8192, stream);                     // zero flags (poisoned 0xAA!)
  if (ringfull)                                            // sentinel-fill the ring
    hipMemsetAsync(qRing, 0xFF, (size_t)rdepth * QSLOT_U32 * 4, stream);
  hipLaunchKernelGGL(rgcn_persist, dim3(NBLK), dim3(NTHR), SMEM_BYTES, stream,
                     X, Af, Wih, Whh, Bias, Wq, Bq, Wd, Bd, Out, qRing, flags,
                     rdepth, ringfull);
}

// Round 11
// 2025.560 us; speedup vs baseline: 1.4196x; 1.0515x over previous
//
#include <hip/hip_runtime.h>
#include <stdint.h>

#define NN 2048
#define TT 365
#define DD 16
#define HH 64
#define NBLK 128      // 16 rows per block, 1 block/CU (LDS-bound)
#define NTHR 1024     // 16 waves
#define SMEM_BYTES 150016
#define QSLOT_U32 65536          // 256 KB per ring slot: [128 blocks][2KB chunk]

typedef __attribute__((ext_vector_type(8))) short bf16x8;
typedef __attribute__((ext_vector_type(4))) float f32x4;
typedef __attribute__((ext_vector_type(4))) unsigned int u32x4;

__device__ __forceinline__ unsigned short f2bf(float f) {
  union { float f; uint32_t u; } z; z.f = f;
  uint32_t r = z.u + 0x7fffu + ((z.u >> 16) & 1u);
  return (unsigned short)(r >> 16);
}
__device__ __forceinline__ float sigmoid_(float x) { return 1.f / (1.f + __expf(-x)); }
__device__ __forceinline__ float tanh_(float x) {
  float ax = fabsf(x);
  float e = __expf(-2.f * ax);
  float r = (1.f - e) / (1.f + e);
  return x < 0.f ? -r : r;
}
__device__ __forceinline__ bf16x8 asbf(u32x4 v) { return __builtin_bit_cast(bf16x8, v); }

// R24: TCC-request-rate fix. Model: per step each of 128 blocks bypass-reads
// 256KB in 16B pieces = 256K req/XCD/step vs ~16 req/cy TCC service -> ~16K
// cy ~= the measured 5.7us/step. Every protocol since R13 issued this same
// request stream — hence the invariant floor. Fix: dedup through L2.
//   Producer: 2KB block-major publish -> vmcnt(0) ack per publishing wave
//   (overlapped with reg-staged out-proj) -> LDS arrival counter -> 4th wave
//   stores per-block MARKER (flags[], monotonic t+2). Data is guaranteed in
//   L3 before the marker is visible.
//   Consumer: wave0 polls 128 markers (2/lane, bypass atomics — tiny) ->
//   __syncthreads (release; doubles as old B2) -> ALL waves plain CACHED
//   dwordx4 loads, NO validation. Safe: no thread cache-touches a ring line
//   before its source's marker was seen, ring slots are write-once fresh
//   addresses, L2 is invalidated at launch -> no stale line can exist.
//   L2 serves 15/16 of the 32MB/step; L3 sees ~256KB/XCD/step + poll.
// Sentinels deleted; host ring memset deleted (kills first-touch RMW fetch).
// Kept from R20/R23: block-major ring, reg-staged Out, X pair-read, sh_g
// epilogue (R22 showed interleave's redundant transcendentals cost more).
// Fallback (!ringfull): same protocol + per-step acquire fence (slot reuse).
__global__ __launch_bounds__(NTHR) __attribute__((amdgpu_waves_per_eu(4, 4)))
void rgcn_persist(
    const float* __restrict__ X, const float* __restrict__ Af,
    const float* __restrict__ Wih, const float* __restrict__ Whh,
    const float* __restrict__ Bias, const float* __restrict__ Wq,
    const float* __restrict__ Bq, const float* __restrict__ Wd,
    const float* __restrict__ Bd, float* __restrict__ Out,
    uint32_t* qRing, uint32_t* flags, int rdepth, int ringfull)
{
  extern __shared__ __align__(16) char smem[];
  unsigned short* afrag = (unsigned short*)smem;                 // [64kc][64ln][8] 65536
  unsigned short* whxT  = (unsigned short*)(smem + 65536);       // [256n][104k]    53248
  unsigned short* wqT   = (unsigned short*)(smem + 118784);      // [64n][72k]       9216
  float*          sh_g  = (float*)(smem + 128000);               // [16][260] fp32  16640
  f32x4*          sh_part = (f32x4*)(smem + 128000);             // union [16][65] 16640
  unsigned short* sh_hx = (unsigned short*)(smem + 144640);      // [16][104] bf16   3328
  unsigned int*   cnt   = (unsigned int*)(smem + 147968);        // publish arrival ctr

  const int tid = threadIdx.x;
  const int w = tid >> 6;        // wave 0..15 (== node row for per-thread work)
  const int c = tid & 63;        // lane
  const int base = blockIdx.x * 16;
  const int m = c & 15, quad = c >> 4;
  const int nt = w & 3, kh = w >> 2;                       // phase B tile coords

  // ---- one-time staging ----
  for (int i = tid; i < 256 * 104; i += NTHR) {            // [WhhT | WihT | 0]
    int n = i / 104, k = i - n * 104;
    float v = (k < 64) ? Whh[k * 256 + n] : (k < 80) ? Wih[(k - 64) * 256 + n] : 0.f;
    whxT[i] = f2bf(v);
  }
  for (int i = tid; i < 64 * 72; i += NTHR) {              // WqT (pad k 64..71 = 0)
    int n = i / 72, k = i - n * 72;
    wqT[i] = (k < 64) ? f2bf(Wq[k * 64 + n]) : (unsigned short)0;
  }
  for (int i = tid; i < 16 * NN; i += NTHR) {              // A -> MFMA A-frag layout
    int r = i >> 11, k = i & (NN - 1);
    afrag[(k >> 5) * 512 + (((k >> 3) & 3) * 16 + r) * 8 + (k & 7)] =
        f2bf(Af[(size_t)(base + r) * NN + k]);
  }
  for (int i = tid; i < 16 * 104; i += NTHR) sh_hx[i] = 0; // h=0, x below, pad=0
  __syncthreads();
  if (c < 16) sh_hx[w * 104 + 64 + c] = f2bf(X[(size_t)(base + w) * (TT * DD) + c]);
  if (tid == 0) *cnt = 0u;
  __syncthreads();

  const float b_i = Bias[c], b_f = Bias[64 + c], b_g = Bias[128 + c], b_o = Bias[192 + c];
  const float wdc = Wd[c], bdc = Bd[0];
  const float bqv = (w < 4) ? Bq[w * 16 + m] : 0.f;        // q-GEMM col bias
  const unsigned short* afp = afrag + (kh * 16) * 512 + c * 8;

  float creg = 0.f, hreg = 0.f;
  float o0 = 0.f, o1 = 0.f, o2 = 0.f, o3 = 0.f, o4 = 0.f, o5 = 0.f;  // Out stage
  float px = 0.f;                                          // X pair register

  // consumer byte-offset within a slot (chunk ch adds ch*4096)
  const uint32_t qoff = (uint32_t)((kh * 32 + (quad >> 1)) * 2048 +
                                   (nt * 16 + m) * 32 + (quad & 1) * 16);
  // producer byte-offset within a slot (block-major chunk)
  const uint32_t poff = (uint32_t)(blockIdx.x * 2048 + (w * 16 + m) * 32 + quad * 8);

  // ---- initial publish: q_0 = tanh(b_q) -> ring slot 0; ack -> marker ----
  if (w < 4) {
    unsigned short qb = f2bf(tanh_(bqv));
    uint32_t pp = (uint32_t)qb | ((uint32_t)qb << 16);
    unsigned long long v = (unsigned long long)pp | ((unsigned long long)pp << 32);
    unsigned long long* dst = (unsigned long long*)((char*)qRing + poff);
    __hip_atomic_store(dst, v, __ATOMIC_RELAXED, __HIP_MEMORY_SCOPE_AGENT);
    asm volatile("s_waitcnt vmcnt(0)" ::: "memory");       // data acked at L3
    if (c == 0) {
      unsigned old = atomicAdd(cnt, 1u);
      if (old == 3u)                                       // 4th wave -> marker
        __hip_atomic_store(&flags[blockIdx.x * 16], 1u,
                           __ATOMIC_RELAXED, __HIP_MEMORY_SCOPE_AGENT);
    }
  }

  int slotR = 0;                                           // read slot for step t
  for (int t = 0; t < TT; ++t) {
    const int slotW = (slotR + 1 == rdepth) ? 0 : slotR + 1;

    // ---- X pair-read: full 128B line every other step ----
    if (((t & 1) == 0) && c < 32) {
      int tt = t + 1 + (c >> 4);                           // lanes 0-15: t+1; 16-31: t+2
      px = (tt < TT) ? X[(size_t)(base + w) * (TT * DD) + tt * DD + (c & 15)] : 0.f;
    }

    f32x4 dg = {0.f, 0.f, 0.f, 0.f};       // gates-GEMM
    {
      const unsigned short* ar = sh_hx + m * 104 + quad * 8;
      const unsigned short* br = whxT + (w * 16 + m) * 104 + quad * 8;
      #pragma unroll
      for (int ch = 0; ch < 3; ++ch)
        dg = __builtin_amdgcn_mfma_f32_16x16x32_bf16(*(const bf16x8*)(ar + ch * 32),
                                                     *(const bf16x8*)(br + ch * 32), dg, 0, 0, 0);
    }
    #pragma unroll
    for (int r = 0; r < 4; ++r)            // D: row=quad*4+r, col=16w+m
      sh_g[(quad * 4 + r) * 260 + w * 16 + m] = dg[r];
    __syncthreads();                       // B1: sh_g ready

    float gi = sigmoid_(b_i + sh_g[w * 260 + c]);
    float gf = sigmoid_(b_f + sh_g[w * 260 + 64 + c]);
    float gg = tanh_  (b_g + sh_g[w * 260 + 128 + c]);
    float go = sigmoid_(b_o + sh_g[w * 260 + 192 + c]);

    // ---- marker wait: wave0 polls all 128 source markers (2 per lane) ----
    if (w == 0) {
      const uint32_t target = (uint32_t)(t + 1);
      for (;;) {
        uint32_t f0 = __hip_atomic_load(&flags[c * 16],
                                        __ATOMIC_RELAXED, __HIP_MEMORY_SCOPE_AGENT);
        uint32_t f1 = __hip_atomic_load(&flags[(64 + c) * 16],
                                        __ATOMIC_RELAXED, __HIP_MEMORY_SCOPE_AGENT);
        if (__all((f0 >= target) && (f1 >= target))) break;
        __builtin_amdgcn_s_sleep(1);
      }
    }
    __syncthreads();                       // release (also = old B2: sh_g reads done)
    if (!ringfull)                         // slot reuse -> invalidate stale L2
      __builtin_amdgcn_fence(__ATOMIC_ACQUIRE, "agent");

    // ---- q acquire: plain CACHED loads, no validation (marker-ordered) ----
    const uint64_t qa =
        (uint64_t)((char*)qRing + (size_t)slotR * (QSLOT_U32 * 4) + qoff);
    u32x4 qv[16];
    #pragma unroll
    for (int ch = 0; ch < 16; ++ch)
      qv[ch] = *(const u32x4*)(qa + (uint64_t)(ch * 4096));

    // ---- phase B: Aq_t via MFMA (dual chain; compiler fine-counts vmcnt) ----
    f32x4 acc0 = {0.f,0.f,0.f,0.f}, acc1 = {0.f,0.f,0.f,0.f};
    #pragma unroll
    for (int ch = 0; ch < 16; ch += 2) {
      acc0 = __builtin_amdgcn_mfma_f32_16x16x32_bf16(
          *(const bf16x8*)(afp + ch * 512), asbf(qv[ch]), acc0, 0, 0, 0);
      acc1 = __builtin_amdgcn_mfma_f32_16x16x32_bf16(
          *(const bf16x8*)(afp + (ch + 1) * 512), asbf(qv[ch + 1]), acc1, 0, 0, 0);
    }
    sh_part[w * 65 + c] = acc0 + acc1;     // [16][65] padded stride
    __syncthreads();                       // B3

    // conflict-free reduce: broadcast b128 reads, vector sum, uniform select
    f32x4 vs;
    {
      const f32x4* sp = sh_part;
      const int li = (w >> 2) * 16 + m;
      f32x4 p0 = sp[(0 * 4 + quad) * 65 + li];
      f32x4 p1 = sp[(1 * 4 + quad) * 65 + li];
      f32x4 p2 = sp[(2 * 4 + quad) * 65 + li];
      f32x4 p3 = sp[(3 * 4 + quad) * 65 + li];
      vs = (p0 + p1) + (p2 + p3);
    }
    float a01 = (w & 1) ? vs[1] : vs[0];
    float a23 = (w & 1) ? vs[3] : vs[2];
    float aqv = (w & 2) ? a23 : a01;

    // ---- update ----
    creg = gf * (creg + aqv) + gi * gg;
    hreg = go * tanh_(creg);
    sh_hx[w * 104 + c] = f2bf(hreg);
    {
      float xw = (t & 1) ? __shfl(px, (c & 15) + 16) : px;
      if (c < 16) sh_hx[w * 104 + 64 + c] = f2bf(xw);
    }
    __syncthreads();                       // B4: h_t visible

    // ---- fused q-GEMM + publish stores (ack deferred past out-proj) ----
    if (w < 4 && t < TT - 1) {
      f32x4 dq = {0.f, 0.f, 0.f, 0.f};
      const unsigned short* ar = sh_hx + m * 104 + quad * 8;
      const unsigned short* br = wqT + (w * 16 + m) * 72 + quad * 8;
      #pragma unroll
      for (int k2 = 0; k2 < 2; ++k2)
        dq = __builtin_amdgcn_mfma_f32_16x16x32_bf16(*(const bf16x8*)(ar + k2 * 32),
                                                     *(const bf16x8*)(br + k2 * 32), dq, 0, 0, 0);
      // D: row=quad*4+r (node), col=16w+m -> 4 consecutive nodes = one 8B store
      unsigned short b0 = f2bf(tanh_(dq[0] + bqv));
      unsigned short b1 = f2bf(tanh_(dq[1] + bqv));
      unsigned short b2 = f2bf(tanh_(dq[2] + bqv));
      unsigned short b3 = f2bf(tanh_(dq[3] + bqv));
      unsigned long long v =
          (unsigned long long)((uint32_t)b0 | ((uint32_t)b1 << 16)) |
          ((unsigned long long)((uint32_t)b2 | ((uint32_t)b3 << 16)) << 32);
      unsigned long long* dst = (unsigned long long*)
          ((char*)qRing + (size_t)slotW * (QSLOT_U32 * 4) + poff);
      __hip_atomic_store(dst, v, __ATOMIC_RELAXED, __HIP_MEMORY_SCOPE_AGENT);
    }

    // ---- output projection -> REGISTER stage (overlaps publish flight) ----
    {
      float red = hreg * wdc;
      #pragma unroll
      for (int off = 32; off; off >>= 1) red += __shfl_xor(red, off);
      float ov = red + bdc;                // every lane has the sum
      switch (t >> 6) {                    // static index (rule #20)
        case 0: if (c == (t & 63)) o0 = ov; break;
        case 1: if (c == (t & 63)) o1 = ov; break;
        case 2: if (c == (t & 63)) o2 = ov; break;
        case 3: if (c == (t & 63)) o3 = ov; break;
        case 4: if (c == (t & 63)) o4 = ov; break;
        default: if (c == (t & 63)) o5 = ov; break;
      }
    }

    // ---- publish ack -> arrival counter -> 4th wave stores marker ----
    if (w < 4 && t < TT - 1) {
      asm volatile("s_waitcnt vmcnt(0)" ::: "memory");     // data acked at L3
      if (c == 0) {
        unsigned old = atomicAdd(cnt, 1u);                 // monotonic, no reset
        if (old == (unsigned)(4 * t + 7))                  // 4th wave this step
          __hip_atomic_store(&flags[blockIdx.x * 16], (uint32_t)(t + 2),
                             __ATOMIC_RELAXED, __HIP_MEMORY_SCOPE_AGENT);
      }
    }

    slotR = slotW;
  }

  // ---- coalesced Out writeback: wave w owns row base+w ----
  {
    float* orow = Out + (size_t)(base + w) * TT;
    orow[c] = o0;
    orow[64 + c] = o1;
    orow[128 + c] = o2;
    orow[192 + c] = o3;
    orow[256 + c] = o4;
    if (320 + c < TT) orow[320 + c] = o5;
  }
}

extern "C" void kernel_launch(void* const* d_in, const int* in_sizes, int n_in,
                              void* d_out, int out_size, void* d_ws, size_t ws_size,
                              hipStream_t stream) {
  const float* X    = (const float*)d_in[0];
  const float* Af   = (const float*)d_in[1];
  const float* Wih  = (const float*)d_in[2];
  const float* Whh  = (const float*)d_in[3];
  const float* Bias = (const float*)d_in[4];
  const float* Wq   = (const float*)d_in[5];
  const float* Bq   = (const float*)d_in[6];
  const float* Wd   = (const float*)d_in[7];
  const float* Bd   = (const float*)d_in[8];
  float* Out = (float*)d_out;

  char* ws = (char*)d_ws;
  uint32_t* flags = (uint32_t*)ws;                         // 128 markers, 64B apart (8 KB)
  uint32_t* qRing = (uint32_t*)(ws + 8192);                // R slots x 256 KB

  long long avail = (long long)ws_size - 8192;
  int rdepth = (int)(avail / (QSLOT_U32 * 4));
  if (rdepth > TT + 1) rdepth = TT + 1;
  if (rdepth < 2) rdepth = 2;
  int ringfull = (rdepth >= TT + 1) ? 1 : 0;

  hipFuncSetAttribute((const void*)rgcn_persist,
                      hipFuncAttributeMaxDynamicSharedMemorySize, SMEM_BYTES);
  hipMemsetAsync(ws, 0, 8192, stream);                     // zero markers (poisoned 0xAA!)
  // NOTE: no ring memset — marker-ordered protocol never reads unwritten ring
  // data, and skipping it removes ~92MB of first-touch RMW fetch.
  hipLaunchKernelGGL(rgcn_persist, dim3(NBLK), dim3(NTHR), SMEM_BYTES, stream,
                     X, Af, Wih, Whh, Bias, Wq, Bq, Wd, Bd, Out, qRing, flags,
                     rdepth, ringfull);
}

// Round 12
// 1848.156 us; speedup vs baseline: 1.5558x; 1.0960x over previous
//
#include <hip/hip_runtime.h>
#include <stdint.h>

#define NN 2048
#define TT 365
#define DD 16
#define HH 64
#define NBLK 128      // 16 rows per block, 1 block/CU (LDS-bound)
#define NTHR 1024     // 16 waves
#define SMEM_BYTES 150016
#define QSLOT_U32 65536          // 256 KB per ring slot: [128 blocks][2KB chunk]

typedef __attribute__((ext_vector_type(8))) short bf16x8;
typedef __attribute__((ext_vector_type(4))) float f32x4;
typedef __attribute__((ext_vector_type(4))) unsigned int u32x4;

__device__ __forceinline__ unsigned short f2bf(float f) {
  union { float f; uint32_t u; } z; z.f = f;
  uint32_t r = z.u + 0x7fffu + ((z.u >> 16) & 1u);
  return (unsigned short)(r >> 16);
}
__device__ __forceinline__ float sigmoid_(float x) { return 1.f / (1.f + __expf(-x)); }
__device__ __forceinline__ float tanh_(float x) {
  float ax = fabsf(x);
  float e = __expf(-2.f * ax);
  float r = (1.f - e) / (1.f + e);
  return x < 0.f ? -r : r;
}
__device__ __forceinline__ bf16x8 asbf(u32x4 v) { return __builtin_bit_cast(bf16x8, v); }

// R25 = R24 (marker-ordered cached q reads @2026us) + three serial-chain cuts:
//  (1) PER-WAVE poll: wave w waits only its 32 sources (blocks [32kh,32kh+32))
//      — removes the wave0-detect + barrier-release hop (~300-700cy).
//  (2) GLOBAL-ATOMIC markers: each publishing wave, after its vmcnt(0) data
//      ack, lane0 fire-and-forget global_atomic_add on flags[bid*16].
//      Consumer target = 4*(t+1) (monotone: init 4, +4/step). Deletes the
//      LDS arrival counter + 4th-wave marker-store leg (~300-400cy).
//  (3) COUNTED q consume: asm-issue all 16 cached dwordx4 (forces them in
//      flight; R24's compiler schedule held only ~4-6 at VGPR=60), then
//      vmcnt(8)+sched_barrier -> MFMA ch 0-7 -> vmcnt(0)+sched_barrier ->
//      MFMA ch 8-15. Counted waits are robust to older outstanding ops
//      (X pair-load, last step's fire-and-forget atomic).
// Kept: block-major write-once ring, cached consumer loads (L2 dedup/XCD),
// reg-staged Out, X pair-read, sh_g epilogue. Fallback (!ringfull): same
// counters + per-step acquire fence + plain loads.
__global__ __launch_bounds__(NTHR) __attribute__((amdgpu_waves_per_eu(4, 4)))
void rgcn_persist(
    const float* __restrict__ X, const float* __restrict__ Af,
    const float* __restrict__ Wih, const float* __restrict__ Whh,
    const float* __restrict__ Bias, const float* __restrict__ Wq,
    const float* __restrict__ Bq, const float* __restrict__ Wd,
    const float* __restrict__ Bd, float* __restrict__ Out,
    uint32_t* qRing, uint32_t* flags, int rdepth, int ringfull)
{
  extern __shared__ __align__(16) char smem[];
  unsigned short* afrag = (unsigned short*)smem;                 // [64kc][64ln][8] 65536
  unsigned short* whxT  = (unsigned short*)(smem + 65536);       // [256n][104k]    53248
  unsigned short* wqT   = (unsigned short*)(smem + 118784);      // [64n][72k]       9216
  float*          sh_g  = (float*)(smem + 128000);               // [16][260] fp32  16640
  f32x4*          sh_part = (f32x4*)(smem + 128000);             // union [16][65] 16640
  unsigned short* sh_hx = (unsigned short*)(smem + 144640);      // [16][104] bf16   3328

  const int tid = threadIdx.x;
  const int w = tid >> 6;        // wave 0..15 (== node row for per-thread work)
  const int c = tid & 63;        // lane
  const int base = blockIdx.x * 16;
  const int m = c & 15, quad = c >> 4;
  const int nt = w & 3, kh = w >> 2;                       // phase B tile coords

  // ---- one-time staging ----
  for (int i = tid; i < 256 * 104; i += NTHR) {            // [WhhT | WihT | 0]
    int n = i / 104, k = i - n * 104;
    float v = (k < 64) ? Whh[k * 256 + n] : (k < 80) ? Wih[(k - 64) * 256 + n] : 0.f;
    whxT[i] = f2bf(v);
  }
  for (int i = tid; i < 64 * 72; i += NTHR) {              // WqT (pad k 64..71 = 0)
    int n = i / 72, k = i - n * 72;
    wqT[i] = (k < 64) ? f2bf(Wq[k * 64 + n]) : (unsigned short)0;
  }
  for (int i = tid; i < 16 * NN; i += NTHR) {              // A -> MFMA A-frag layout
    int r = i >> 11, k = i & (NN - 1);
    afrag[(k >> 5) * 512 + (((k >> 3) & 3) * 16 + r) * 8 + (k & 7)] =
        f2bf(Af[(size_t)(base + r) * NN + k]);
  }
  for (int i = tid; i < 16 * 104; i += NTHR) sh_hx[i] = 0; // h=0, x below, pad=0
  __syncthreads();
  if (c < 16) sh_hx[w * 104 + 64 + c] = f2bf(X[(size_t)(base + w) * (TT * DD) + c]);
  __syncthreads();

  const float b_i = Bias[c], b_f = Bias[64 + c], b_g = Bias[128 + c], b_o = Bias[192 + c];
  const float wdc = Wd[c], bdc = Bd[0];
  const float bqv = (w < 4) ? Bq[w * 16 + m] : 0.f;        // q-GEMM col bias
  const unsigned short* afp = afrag + (kh * 16) * 512 + c * 8;

  float creg = 0.f, hreg = 0.f;
  float o0 = 0.f, o1 = 0.f, o2 = 0.f, o3 = 0.f, o4 = 0.f, o5 = 0.f;  // Out stage
  float px = 0.f;                                          // X pair register

  // consumer byte-offset within a slot (chunk ch adds ch*4096)
  const uint32_t qoff = (uint32_t)((kh * 32 + (quad >> 1)) * 2048 +
                                   (nt * 16 + m) * 32 + (quad & 1) * 16);
  // producer byte-offset within a slot (block-major chunk)
  const uint32_t poff = (uint32_t)(blockIdx.x * 2048 + (w * 16 + m) * 32 + quad * 8);

  // ---- initial publish: q_0 -> ring slot 0; ack -> atomic marker (+1) ----
  if (w < 4) {
    unsigned short qb = f2bf(tanh_(bqv));
    uint32_t pp = (uint32_t)qb | ((uint32_t)qb << 16);
    unsigned long long v = (unsigned long long)pp | ((unsigned long long)pp << 32);
    unsigned long long* dst = (unsigned long long*)((char*)qRing + poff);
    __hip_atomic_store(dst, v, __ATOMIC_RELAXED, __HIP_MEMORY_SCOPE_AGENT);
    asm volatile("s_waitcnt vmcnt(0)" ::: "memory");       // data acked at L3
    if (c == 0) atomicAdd(&flags[blockIdx.x * 16], 1u);    // fire-and-forget
  }

  int slotR = 0;                                           // read slot for step t
  for (int t = 0; t < TT; ++t) {
    const int slotW = (slotR + 1 == rdepth) ? 0 : slotR + 1;

    // ---- X pair-read: full 128B line every other step ----
    if (((t & 1) == 0) && c < 32) {
      int tt = t + 1 + (c >> 4);                           // lanes 0-15: t+1; 16-31: t+2
      px = (tt < TT) ? X[(size_t)(base + w) * (TT * DD) + tt * DD + (c & 15)] : 0.f;
    }

    f32x4 dg = {0.f, 0.f, 0.f, 0.f};       // gates-GEMM
    {
      const unsigned short* ar = sh_hx + m * 104 + quad * 8;
      const unsigned short* br = whxT + (w * 16 + m) * 104 + quad * 8;
      #pragma unroll
      for (int ch = 0; ch < 3; ++ch)
        dg = __builtin_amdgcn_mfma_f32_16x16x32_bf16(*(const bf16x8*)(ar + ch * 32),
                                                     *(const bf16x8*)(br + ch * 32), dg, 0, 0, 0);
    }
    #pragma unroll
    for (int r = 0; r < 4; ++r)            // D: row=quad*4+r, col=16w+m
      sh_g[(quad * 4 + r) * 260 + w * 16 + m] = dg[r];
    __syncthreads();                       // B1: sh_g ready

    float gi = sigmoid_(b_i + sh_g[w * 260 + c]);
    float gf = sigmoid_(b_f + sh_g[w * 260 + 64 + c]);
    float gg = tanh_  (b_g + sh_g[w * 260 + 128 + c]);
    float go = sigmoid_(b_o + sh_g[w * 260 + 192 + c]);
    __syncthreads();                       // B2: sh_g reads done (sh_part reuse safe)

    // ---- per-wave marker wait: my 32 sources reached 4*(t+1) ----
    {
      const uint32_t target = 4u * (uint32_t)(t + 1);
      const int src = 32 * kh + (c & 31);                  // lanes 32..63 duplicate
      for (;;) {
        uint32_t f = __hip_atomic_load(&flags[src * 16],
                                       __ATOMIC_RELAXED, __HIP_MEMORY_SCOPE_AGENT);
        if (__all((int)(f >= target))) break;
        __builtin_amdgcn_s_sleep(1);
      }
    }
    if (!ringfull)                         // slot reuse -> invalidate stale L2
      __builtin_amdgcn_fence(__ATOMIC_ACQUIRE, "agent");

    // ---- q acquire: cached loads, counted-vmcnt two-batch consume ----
    const uint64_t qa =
        (uint64_t)((char*)qRing + (size_t)slotR * (QSLOT_U32 * 4) + qoff);
    u32x4 qv[16];
    f32x4 acc0 = {0.f,0.f,0.f,0.f}, acc1 = {0.f,0.f,0.f,0.f};
    if (ringfull) {
      #pragma unroll
      for (int ch = 0; ch < 16; ++ch)                      // issue all 16, in flight
        asm volatile("global_load_dwordx4 %0, %1, off"
                     : "=v"(qv[ch]) : "v"(qa + (uint64_t)(ch * 4096)) : "memory");
      asm volatile("s_waitcnt vmcnt(8)" ::: "memory");     // chunks 0..7 landed
      __builtin_amdgcn_sched_barrier(0);                   // rule #18
      #pragma unroll
      for (int ch = 0; ch < 8; ch += 2) {
        acc0 = __builtin_amdgcn_mfma_f32_16x16x32_bf16(
            *(const bf16x8*)(afp + ch * 512), asbf(qv[ch]), acc0, 0, 0, 0);
        acc1 = __builtin_amdgcn_mfma_f32_16x16x32_bf16(
            *(const bf16x8*)(afp + (ch + 1) * 512), asbf(qv[ch + 1]), acc1, 0, 0, 0);
      }
      asm volatile("s_waitcnt vmcnt(0)" ::: "memory");     // chunks 8..15 landed
      __builtin_amdgcn_sched_barrier(0);
      #pragma unroll
      for (int ch = 8; ch < 16; ch += 2) {
        acc0 = __builtin_amdgcn_mfma_f32_16x16x32_bf16(
            *(const bf16x8*)(afp + ch * 512), asbf(qv[ch]), acc0, 0, 0, 0);
        acc1 = __builtin_amdgcn_mfma_f32_16x16x32_bf16(
            *(const bf16x8*)(afp + (ch + 1) * 512), asbf(qv[ch + 1]), acc1, 0, 0, 0);
      }
    } else {
      #pragma unroll
      for (int ch = 0; ch < 16; ++ch)
        qv[ch] = *(const u32x4*)(qa + (uint64_t)(ch * 4096));
      #pragma unroll
      for (int ch = 0; ch < 16; ch += 2) {
        acc0 = __builtin_amdgcn_mfma_f32_16x16x32_bf16(
            *(const bf16x8*)(afp + ch * 512), asbf(qv[ch]), acc0, 0, 0, 0);
        acc1 = __builtin_amdgcn_mfma_f32_16x16x32_bf16(
            *(const bf16x8*)(afp + (ch + 1) * 512), asbf(qv[ch + 1]), acc1, 0, 0, 0);
      }
    }
    sh_part[w * 65 + c] = acc0 + acc1;     // [16][65] padded stride
    __syncthreads();                       // B3

    // conflict-free reduce: broadcast b128 reads, vector sum, uniform select
    f32x4 vs;
    {
      const f32x4* sp = sh_part;
      const int li = (w >> 2) * 16 + m;
      f32x4 p0 = sp[(0 * 4 + quad) * 65 + li];
      f32x4 p1 = sp[(1 * 4 + quad) * 65 + li];
      f32x4 p2 = sp[(2 * 4 + quad) * 65 + li];
      f32x4 p3 = sp[(3 * 4 + quad) * 65 + li];
      vs = (p0 + p1) + (p2 + p3);
    }
    float a01 = (w & 1) ? vs[1] : vs[0];
    float a23 = (w & 1) ? vs[3] : vs[2];
    float aqv = (w & 2) ? a23 : a01;

    // ---- update ----
    creg = gf * (creg + aqv) + gi * gg;
    hreg = go * tanh_(creg);
    sh_hx[w * 104 + c] = f2bf(hreg);
    {
      float xw = (t & 1) ? __shfl(px, (c & 15) + 16) : px;
      if (c < 16) sh_hx[w * 104 + 64 + c] = f2bf(xw);
    }
    __syncthreads();                       // B4: h_t visible

    // ---- fused q-GEMM + publish stores (ack deferred past out-proj) ----
    if (w < 4 && t < TT - 1) {
      f32x4 dq = {0.f, 0.f, 0.f, 0.f};
      const unsigned short* ar = sh_hx + m * 104 + quad * 8;
      const unsigned short* br = wqT + (w * 16 + m) * 72 + quad * 8;
      #pragma unroll
      for (int k2 = 0; k2 < 2; ++k2)
        dq = __builtin_amdgcn_mfma_f32_16x16x32_bf16(*(const bf16x8*)(ar + k2 * 32),
                                                     *(const bf16x8*)(br + k2 * 32), dq, 0, 0, 0);
      // D: row=quad*4+r (node), col=16w+m -> 4 consecutive nodes = one 8B store
      unsigned short b0 = f2bf(tanh_(dq[0] + bqv));
      unsigned short b1 = f2bf(tanh_(dq[1] + bqv));
      unsigned short b2 = f2bf(tanh_(dq[2] + bqv));
      unsigned short b3 = f2bf(tanh_(dq[3] + bqv));
      unsigned long long v =
          (unsigned long long)((uint32_t)b0 | ((uint32_t)b1 << 16)) |
          ((unsigned long long)((uint32_t)b2 | ((uint32_t)b3 << 16)) << 32);
      unsigned long long* dst = (unsigned long long*)
          ((char*)qRing + (size_t)slotW * (QSLOT_U32 * 4) + poff);
      __hip_atomic_store(dst, v, __ATOMIC_RELAXED, __HIP_MEMORY_SCOPE_AGENT);
    }

    // ---- output projection -> REGISTER stage (overlaps publish flight) ----
    {
      float red = hreg * wdc;
      #pragma unroll
      for (int off = 32; off; off >>= 1) red += __shfl_xor(red, off);
      float ov = red + bdc;                // every lane has the sum
      switch (t >> 6) {                    // static index (rule #20)
        case 0: if (c == (t & 63)) o0 = ov; break;
        case 1: if (c == (t & 63)) o1 = ov; break;
        case 2: if (c == (t & 63)) o2 = ov; break;
        case 3: if (c == (t & 63)) o3 = ov; break;
        case 4: if (c == (t & 63)) o4 = ov; break;
        default: if (c == (t & 63)) o5 = ov; break;
      }
    }

    // ---- publish ack -> per-wave fire-and-forget atomic marker (+1) ----
    if (w < 4 && t < TT - 1) {
      asm volatile("s_waitcnt vmcnt(0)" ::: "memory");     // data acked at L3
      if (c == 0) atomicAdd(&flags[blockIdx.x * 16], 1u);  // counter -> 4*(t+2)
    }

    slotR = slotW;
  }

  // ---- coalesced Out writeback: wave w owns row base+w ----
  {
    float* orow = Out + (size_t)(base + w) * TT;
    orow[c] = o0;
    orow[64 + c] = o1;
    orow[128 + c] = o2;
    orow[192 + c] = o3;
    orow[256 + c] = o4;
    if (320 + c < TT) orow[320 + c] = o5;
  }
}

extern "C" void kernel_launch(void* const* d_in, const int* in_sizes, int n_in,
                              void* d_out, int out_size, void* d_ws, size_t ws_size,
                              hipStream_t stream) {
  const float* X    = (const float*)d_in[0];
  const float* Af   = (const float*)d_in[1];
  const float* Wih  = (const float*)d_in[2];
  const float* Whh  = (const float*)d_in[3];
  const float* Bias = (const float*)d_in[4];
  const float* Wq   = (const float*)d_in[5];
  const float* Bq   = (const float*)d_in[6];
  const float* Wd   = (const float*)d_in[7];
  const float* Bd   = (const float*)d_in[8];
  float* Out = (float*)d_out;

  char* ws = (char*)d_ws;
  uint32_t* flags = (uint32_t*)ws;                         // 128 atomic markers, 64B apart
  uint32_t* qRing = (uint32_t*)(ws + 8192);                // R slots x 256 KB

  long long avail = (long long)ws_size - 8192;
  int rdepth = (int)(avail / (QSLOT_U32 * 4));
  if (rdepth > TT + 1) rdepth = TT + 1;
  if (rdepth < 2) rdepth = 2;
  int ringfull = (rdepth >= TT + 1) ? 1 : 0;

  hipFuncSetAttribute((const void*)rgcn_persist,
                      hipFuncAttributeMaxDynamicSharedMemorySize, SMEM_BYTES);
  hipMemsetAsync(ws, 0, 8192, stream);                     // zero markers (poisoned 0xAA!)
  // no ring memset: marker-ordered protocol never reads unwritten ring data
  hipLaunchKernelGGL(rgcn_persist, dim3(NBLK), dim3(NTHR), SMEM_BYTES, stream,
                     X, Af, Wih, Whh, Bias, Wq, Bq, Wd, Bd, Out, qRing, flags,
                     rdepth, ringfull);
}